// Round 10
// baseline (58.041 us; speedup 1.0000x reference)
//
#include <hip/hip_runtime.h>

// Problem constants (from reference setup_inputs)
#define E_TOT 1000000
#define D_DIM 128
#define C_CAP 262144
#define N_IDS 16384
#define NB 102        // buckets: [key<0], keys 0..99, [key>=100]; 255 = protected
#define NW 31250      // miss bit words: E/32
#define SB 256        // slot blocks (C / SPB)
#define NTHR 512
#define SPB 1024      // slots per slot-block (2 per thread)
#define CHK 52        // blockHist chunk: 5 chunks cover 256 blocks
#define NGB (N_IDS / 8)   // gather blocks (one wave per row)
#define TB 32             // translate blocks: 32*512 == N_IDS
#define WPT 62            // missBits words owned per translate thread

static_assert(SB * SPB == C_CAP, "geometry");
static_assert(5 * CHK >= SB, "geometry");
static_assert(5 * NB <= NTHR, "geometry");
static_assert(TB * NTHR == N_IDS, "geometry");
static_assert(NTHR * WPT >= NW, "geometry");

// EXACT per-byte equality count (carry-free SWAR; validated R4..R9)
__device__ __forceinline__ int cnt_eq(unsigned w, unsigned pat) {
    unsigned x = w ^ pat;
    unsigned y = ((x & 0x7F7F7F7Fu) + 0x7F7F7F7Fu) | x | 0x7F7F7F7Fu;
    return __popc(~y & 0x80808080u);
}

__device__ __forceinline__ int bucket_of(int crow, const int* __restrict__ freq) {
    int key = (crow < 0) ? -1 : freq[crow < E_TOT ? crow : (E_TOT - 1)];
    return (key < 0) ? 0 : (key >= 100 ? 101 : key + 1);
}

// 512-thread exclusive block scan (block-uniform entry only)
__device__ __forceinline__ int block_exscan(int v, int tid, int* lds8) {
    int lane = tid & 63, wv = tid >> 6;
    int incl = v;
#pragma unroll
    for (int o = 1; o < 64; o <<= 1) {
        int u = __shfl_up(incl, o, 64);
        if (lane >= o) incl += u;
    }
    if (lane == 63) lds8[wv] = incl;
    __syncthreads();
    int wsum = 0;
    for (int w = 0; w < wv; ++w) wsum += lds8[w];
    __syncthreads();
    return wsum + incl - v;
}

// ---------------------------------------------------------------------------
// D2: blocks [0,NGB):          full row gather (FIRST: HBM loads start early)
//     blocks [NGB,NGB+SB):     RAW bucket bytes + per-block RAW hist
//     blocks [NGB+SB,+32):     scatter — bitmask OR + first-setter protHist
__global__ __launch_bounds__(NTHR) void stage1_k(
    const int* __restrict__ ids, const int* __restrict__ idx_map,
    const int* __restrict__ inv, const int* __restrict__ cidx,
    const int* __restrict__ freq, const float* __restrict__ weight,
    const float* __restrict__ cuda_weight, float* __restrict__ out,
    unsigned* __restrict__ protBits, unsigned* __restrict__ missBits,
    unsigned short* __restrict__ bucketArr2,
    int* __restrict__ rawHist, int* __restrict__ protHist) {
    const int tid = threadIdx.x, bid = blockIdx.x;
    if (bid < NGB) {
        // gather: one wave per row; hit rows also store their slot float
        const int i = bid * 8 + (tid >> 6);
        const int lane = tid & 63;
        int id = ids[i];
        int row = (id >= 0 && id < E_TOT) ? idx_map[id] : 0;
        row = row < 0 ? 0 : (row >= E_TOT ? E_TOT - 1 : row);
        int s0 = inv[row];
        const float* src;
        if (s0 >= 0) {
            if (lane == 0) out[i] = (float)s0;
            src = cuda_weight + (size_t)s0 * D_DIM;
        } else {
            src = weight + (size_t)row * D_DIM; // miss data = weight[row]
        }
        const float2* s2 = (const float2*)src;
        float2* d2 = (float2*)(out + N_IDS + (size_t)i * D_DIM);
        d2[lane] = s2[lane]; // 64 lanes x float2 = 128 floats
    } else if (bid < NGB + SB) {
        const int sb = bid - NGB;
        __shared__ int waveHist[8][NB];
        for (int k = tid; k < 8 * NB; k += NTHR) ((int*)waveHist)[k] = 0;
        __syncthreads();
        const int s0 = sb * SPB + 2 * tid;
        const int2 cr = *(const int2*)(cidx + s0);
        const int b0 = bucket_of(cr.x, freq);
        const int b1 = bucket_of(cr.y, freq);
        const int wv = tid >> 6;
        atomicAdd(&waveHist[wv][b0], 1);
        atomicAdd(&waveHist[wv][b1], 1);
        bucketArr2[sb * (SPB / 2) + tid] = (unsigned short)(b0 | (b1 << 8));
        __syncthreads();
        if (tid < NB) {
            int s = 0;
#pragma unroll
            for (int w = 0; w < 8; ++w) s += waveHist[w][tid];
            rawHist[sb * NB + tid] = s; // plain store (replay-safe)
        }
    } else {
        const int i = (bid - NGB - SB) * NTHR + tid; // < N_IDS
        int id = ids[i];
        if (id < 0 || id >= E_TOT) return;
        int row = idx_map[id];
        if (row < 0 || row >= E_TOT) return;
        int s = inv[row];
        if (s >= 0) {
            if (s < C_CAP) {
                unsigned bit = 1u << (s & 31);
                unsigned old = atomicOr(&protBits[s >> 5], bit);
                if (!(old & bit)) { // exactly one thread per hit slot
                    int b = bucket_of(cidx[s], freq);
                    atomicAdd(&protHist[(s >> 10) * NB + b], 1); // sparse
                }
            }
        } else {
            atomicOr(&missBits[row >> 5], 1u << (row & 31));
        }
    }
}

// ---------------------------------------------------------------------------
// D3: stable placement -> order[pos] = slot (plain stores; pos < N_IDS only —
// larger positions are never consumed since m <= N_IDS)
__global__ __launch_bounds__(NTHR) void place_k(
    const unsigned short* __restrict__ bucketArr2,
    const unsigned* __restrict__ protBits,
    const int* __restrict__ rawHist, const int* __restrict__ protHist,
    int* __restrict__ order) {
    const int tid = threadIdx.x, bid = blockIdx.x;
    __shared__ unsigned char ldsB[SPB];
    __shared__ unsigned protW[SPB / 32];
    __shared__ int waveHist[8][NB];
    __shared__ int partBefore[5][NB];
    __shared__ int partTotal[5][NB];
    __shared__ int bstart[NB];
    __shared__ int before[NB];
    if (tid < SPB / 32) protW[tid] = protBits[bid * (SPB / 32) + tid];
    for (int k = tid; k < 8 * NB; k += NTHR) ((int*)waveHist)[k] = 0;
    __syncthreads();
    const unsigned short pk = bucketArr2[bid * (SPB / 2) + tid];
    const unsigned pw = protW[tid >> 4];
    int b0 = ((pw >> ((2 * tid) & 31)) & 1u) ? 255 : (pk & 0xFF);
    int b1 = ((pw >> ((2 * tid + 1) & 31)) & 1u) ? 255 : (pk >> 8);
    ldsB[2 * tid] = (unsigned char)b0;
    ldsB[2 * tid + 1] = (unsigned char)b1;
    const int wv = tid >> 6, lane = tid & 63;
    if (b0 != 255) atomicAdd(&waveHist[wv][b0], 1);
    if (b1 != 255) atomicAdd(&waveHist[wv][b1], 1);
    // stream masked hist (raw - prot): totals + prefix over blocks < bid
    if (tid < 5 * NB) {
        const int c = tid / NB, b = tid % NB; // coalesced in b
        int lo = c * CHK, hi = lo + CHK;
        if (hi > SB) hi = SB;
        int tot = 0, bef = 0;
        for (int blk = lo; blk < hi; ++blk) {
            int v = rawHist[blk * NB + b] - protHist[blk * NB + b];
            tot += v;
            if (blk < bid) bef += v;
        }
        partTotal[c][b] = tot;
        partBefore[c][b] = bef;
    }
    __syncthreads();
    if (tid < NB) {
        int t = 0, bf = 0;
#pragma unroll
        for (int c = 0; c < 5; ++c) {
            t += partTotal[c][tid];
            bf += partBefore[c][tid];
        }
        bstart[tid] = t; // temp: per-bucket grand total (masked)
        before[tid] = bf;
    }
    __syncthreads();
    if (tid == 0) { // exclusive scan of totals -> bucket starts
        int run = 0;
        for (int b = 0; b < NB; ++b) {
            int t = bstart[b];
            bstart[b] = run;
            run += t;
        }
    }
    __syncthreads();
    // in-wave stable ranks over the wave's 128-byte ldsB segment
    const unsigned* wp = (const unsigned*)&ldsB[wv * 128];
    unsigned patA = 0x01010101u * (unsigned)b0;
    unsigned patB = 0x01010101u * (unsigned)b1;
    int full = lane >> 1;
    int cA = 0, cB = 0;
    for (int w = 0; w < full; ++w) {
        unsigned x = wp[w];
        cA += cnt_eq(x, patA);
        cB += cnt_eq(x, patB);
    }
    if (lane & 1) { // 2 leftover bytes; upper -> 0xFF (never match b<=101)
        unsigned x = wp[full] | 0xFFFF0000u;
        cA += cnt_eq(x, patA);
        cB += cnt_eq(x, patB);
    }
    int pA = 0, pB = 0;
    for (int w = 0; w < wv; ++w) {
        pA += (b0 != 255) ? waveHist[w][b0] : 0;
        pB += (b1 != 255) ? waveHist[w][b1] : 0;
    }
    const int s0 = bid * SPB + 2 * tid;
    if (b0 != 255) {
        int pos = bstart[b0] + before[b0] + pA + cA;
        if (pos < N_IDS) order[pos] = s0;
    }
    if (b1 != 255) {
        int pos = bstart[b1] + before[b1] + pB + cB + ((b0 == b1) ? 1 : 0);
        if (pos < N_IDS) order[pos] = s0 + 1;
    }
}

// ---------------------------------------------------------------------------
// D4: miss-slot translation — contiguous-slice self-rank (validated R9),
// plain order[] load (boundary guarantees visibility). 32 blocks.
__global__ __launch_bounds__(NTHR) void translate_k(
    const int* __restrict__ ids, const int* __restrict__ idx_map,
    const int* __restrict__ inv, const unsigned* __restrict__ missBits,
    const int* __restrict__ order, float* __restrict__ out) {
    __shared__ int lds8[8];
    __shared__ int baseLds[NTHR];
    const int tid = threadIdx.x, bid = blockIdx.x;
    const int w0 = tid * WPT;
    int sum = 0;
    for (int k = 0; k < WPT; ++k) {
        int w = w0 + k;
        if (w < NW) sum += __popc(missBits[w]);
    }
    baseLds[tid] = block_exscan(sum, tid, lds8);
    __syncthreads();
    const int i = bid * NTHR + tid; // < N_IDS
    int id = ids[i];
    int row = (id >= 0 && id < E_TOT) ? idx_map[id] : 0;
    row = row < 0 ? 0 : (row >= E_TOT ? E_TOT - 1 : row);
    if (inv[row] < 0) {
        const int w = row >> 5;
        const int owner = w / WPT;
        int rank = baseLds[owner];
        for (int k = owner * WPT; k < w; ++k)
            rank += __popc(missBits[k]);
        rank += __popc(missBits[w] & ((1u << (row & 31)) - 1u));
        rank = rank < 0 ? 0 : (rank >= N_IDS ? N_IDS - 1 : rank);
        out[i] = (float)order[rank];
    }
}

// ---------------------------------------------------------------------------
extern "C" void kernel_launch(void* const* d_in, const int* in_sizes, int n_in,
                              void* d_out, int out_size, void* d_ws, size_t ws_size,
                              hipStream_t stream) {
    const int* ids     = (const int*)d_in[0];
    const int* idx_map = (const int*)d_in[1];
    const int* cidx    = (const int*)d_in[2]; // cached_idx_map
    const int* inv     = (const int*)d_in[3]; // inverted_cached_idx
    const int* freq    = (const int*)d_in[4]; // freq_cnter
    const float* weight      = (const float*)d_in[5];
    const float* cuda_weight = (const float*)d_in[6];
    float* out = (float*)d_out;

    unsigned char* ws = (unsigned char*)d_ws;
    size_t o = 0;
    auto take = [&](size_t bytes) {
        size_t r = o;
        o += (bytes + 255) & ~(size_t)255;
        return r;
    };
    // ---- zero region (single contiguous memset) ----
    unsigned* protBits = (unsigned*)(ws + take(C_CAP / 8));           // 32 KB
    unsigned* missBits = (unsigned*)(ws + take((size_t)NW * 4));      // 125 KB
    int* protHist      = (int*)(ws + take((size_t)SB * NB * 4));      // 104 KB
    size_t zbytes = o;
    // ---- non-zeroed (plain stores every call; replay-safe) ----
    unsigned short* bucketArr2 = (unsigned short*)(ws + take(C_CAP)); // 256 KB
    int* rawHist = (int*)(ws + take((size_t)SB * NB * 4));            // 104 KB
    int* order   = (int*)(ws + take((size_t)N_IDS * 4));              // 64 KB
    (void)ws_size; (void)in_sizes; (void)n_in; (void)out_size;

    // D1: zero masks + protHist
    hipMemsetAsync(ws, 0, zbytes, stream);

    // D2: gather (0..2047) || raw hists (2048..2303) || scatter (2304..2335)
    stage1_k<<<NGB + SB + 32, NTHR, 0, stream>>>(
        ids, idx_map, inv, cidx, freq, weight, cuda_weight, out,
        protBits, missBits, bucketArr2, rawHist, protHist);

    // D3: stable placement (256 blocks)
    place_k<<<SB, NTHR, 0, stream>>>(bucketArr2, protBits, rawHist, protHist,
                                     order);

    // D4: miss-slot translation (32 blocks)
    translate_k<<<TB, NTHR, 0, stream>>>(ids, idx_map, inv, missBits, order,
                                         out);
}

// Round 11
// 35.908 us; speedup vs baseline: 1.6164x; 1.6164x over previous
//
#include <hip/hip_runtime.h>

// Problem constants (from reference setup_inputs)
#define E_TOT 1000000
#define D_DIM 128
#define C_CAP 262144
#define N_IDS 16384
#define NB 102        // buckets: [key<0], keys 0..99, [key>=100]; 255 = protected
#define NW 31250      // miss bit words: E/32
#define SB 256        // slot blocks (C / SPB)
#define NTHR 512
#define SPB 1024      // slots per slot-block (2 per thread)
#define MWB 62        // miss chunk-scan blocks: 62*512 >= NW
#define CHK 52        // rawHist chunk: 5 chunks cover 256 blocks
#define NGB (N_IDS / 8)   // final blocks (one wave per row)

static_assert(SB * SPB == C_CAP, "geometry");
static_assert(MWB * NTHR >= NW, "geometry");
static_assert(5 * CHK >= SB, "geometry");
static_assert(5 * NB <= NTHR, "geometry");

// EXACT per-byte equality count (carry-free SWAR; validated R4..R10)
__device__ __forceinline__ int cnt_eq(unsigned w, unsigned pat) {
    unsigned x = w ^ pat;
    unsigned y = ((x & 0x7F7F7F7Fu) + 0x7F7F7F7Fu) | x | 0x7F7F7F7Fu;
    return __popc(~y & 0x80808080u);
}

__device__ __forceinline__ int bucket_of(int crow, const int* __restrict__ freq) {
    int key = (crow < 0) ? -1 : freq[crow < E_TOT ? crow : (E_TOT - 1)];
    return (key < 0) ? 0 : (key >= 100 ? 101 : key + 1);
}

// 512-thread exclusive block scan (block-uniform entry only)
__device__ __forceinline__ int block_exscan(int v, int tid, int* lds8) {
    int lane = tid & 63, wv = tid >> 6;
    int incl = v;
#pragma unroll
    for (int o = 1; o < 64; o <<= 1) {
        int u = __shfl_up(incl, o, 64);
        if (lane >= o) incl += u;
    }
    if (lane == 63) lds8[wv] = incl;
    __syncthreads();
    int wsum = 0;
    for (int w = 0; w < wv; ++w) wsum += lds8[w];
    __syncthreads();
    return wsum + incl - v;
}

// ---------------------------------------------------------------------------
// D2: blocks [0,SB):    RAW bucket bytes; per-block hist row via atomicAdd
//     blocks [SB,SB+32): scatter — bitmask OR + first-setter rawHist -1
// (hist rows are per-block distinct; scatter decrements are sparse; all
//  contributions commutative atomics on a zeroed array => deterministic)
__global__ __launch_bounds__(NTHR) void stage1_k(
    const int* __restrict__ ids, const int* __restrict__ idx_map,
    const int* __restrict__ inv, const int* __restrict__ cidx,
    const int* __restrict__ freq,
    unsigned* __restrict__ protBits, unsigned* __restrict__ missBits,
    unsigned short* __restrict__ bucketArr2, int* __restrict__ rawHist) {
    const int tid = threadIdx.x, bid = blockIdx.x;
    if (bid < SB) {
        __shared__ int waveHist[8][NB];
        for (int k = tid; k < 8 * NB; k += NTHR) ((int*)waveHist)[k] = 0;
        __syncthreads();
        const int s0 = bid * SPB + 2 * tid;
        const int2 cr = *(const int2*)(cidx + s0);
        const int b0 = bucket_of(cr.x, freq);
        const int b1 = bucket_of(cr.y, freq);
        const int wv = tid >> 6;
        atomicAdd(&waveHist[wv][b0], 1);
        atomicAdd(&waveHist[wv][b1], 1);
        bucketArr2[bid * (SPB / 2) + tid] = (unsigned short)(b0 | (b1 << 8));
        __syncthreads();
        if (tid < NB) {
            int s = 0;
#pragma unroll
            for (int w = 0; w < 8; ++w) s += waveHist[w][tid];
            if (s) atomicAdd(&rawHist[bid * NB + tid], s); // own row
        }
    } else {
        const int i = (bid - SB) * NTHR + tid; // < N_IDS
        int id = ids[i];
        if (id < 0 || id >= E_TOT) return;
        int row = idx_map[id];
        if (row < 0 || row >= E_TOT) return;
        int s = inv[row];
        if (s >= 0) {
            if (s < C_CAP) {
                unsigned bit = 1u << (s & 31);
                unsigned old = atomicOr(&protBits[s >> 5], bit);
                if (!(old & bit)) { // exactly one thread per hit slot
                    int b = bucket_of(cidx[s], freq);
                    atomicAdd(&rawHist[(s >> 10) * NB + b], -1); // sparse
                }
            }
        } else {
            atomicOr(&missBits[row >> 5], 1u << (row & 31));
        }
    }
}

// ---------------------------------------------------------------------------
// D3: blocks [0,SB): stable placement -> order[pos] = slot (plain stores,
//                    pos < N_IDS only — larger positions never consumed)
//     blocks [SB,SB+MWB): miss popcount chunk scans (chunk-local)
__global__ __launch_bounds__(NTHR) void stage2_k(
    const unsigned short* __restrict__ bucketArr2,
    const unsigned* __restrict__ protBits, const int* __restrict__ rawHist,
    const unsigned* __restrict__ missBits,
    int* __restrict__ wordPrefix, int* __restrict__ blockSumMiss,
    int* __restrict__ order) {
    const int tid = threadIdx.x, bid = blockIdx.x;
    if (bid < SB) {
        __shared__ unsigned char ldsB[SPB];
        __shared__ unsigned protW[SPB / 32];
        __shared__ int waveHist[8][NB];
        __shared__ int partBefore[5][NB];
        __shared__ int partTotal[5][NB];
        __shared__ int bstart[NB];
        __shared__ int before[NB];
        if (tid < SPB / 32) protW[tid] = protBits[bid * (SPB / 32) + tid];
        for (int k = tid; k < 8 * NB; k += NTHR) ((int*)waveHist)[k] = 0;
        __syncthreads();
        const unsigned short pk = bucketArr2[bid * (SPB / 2) + tid];
        const unsigned pw = protW[tid >> 4];
        int b0 = ((pw >> ((2 * tid) & 31)) & 1u) ? 255 : (pk & 0xFF);
        int b1 = ((pw >> ((2 * tid + 1) & 31)) & 1u) ? 255 : (pk >> 8);
        ldsB[2 * tid] = (unsigned char)b0;
        ldsB[2 * tid + 1] = (unsigned char)b1;
        const int wv = tid >> 6, lane = tid & 63;
        if (b0 != 255) atomicAdd(&waveHist[wv][b0], 1);
        if (b1 != 255) atomicAdd(&waveHist[wv][b1], 1);
        // stream corrected hist: per-bucket totals + prefix over blocks < bid
        if (tid < 5 * NB) {
            const int c = tid / NB, b = tid % NB; // coalesced in b
            int lo = c * CHK, hi = lo + CHK;
            if (hi > SB) hi = SB;
            int tot = 0, bef = 0;
            for (int blk = lo; blk < hi; ++blk) {
                int v = rawHist[blk * NB + b];
                tot += v;
                if (blk < bid) bef += v;
            }
            partTotal[c][b] = tot;
            partBefore[c][b] = bef;
        }
        __syncthreads();
        if (tid < NB) {
            int t = 0, bf = 0;
#pragma unroll
            for (int c = 0; c < 5; ++c) {
                t += partTotal[c][tid];
                bf += partBefore[c][tid];
            }
            bstart[tid] = t; // temp: per-bucket grand total (corrected)
            before[tid] = bf;
        }
        __syncthreads();
        if (tid == 0) { // exclusive scan of totals -> bucket starts
            int run = 0;
            for (int b = 0; b < NB; ++b) {
                int t = bstart[b];
                bstart[b] = run;
                run += t;
            }
        }
        __syncthreads();
        // in-wave stable ranks over the wave's 128-byte ldsB segment
        const unsigned* wp = (const unsigned*)&ldsB[wv * 128];
        unsigned patA = 0x01010101u * (unsigned)b0;
        unsigned patB = 0x01010101u * (unsigned)b1;
        int full = lane >> 1;
        int cA = 0, cB = 0;
        for (int w = 0; w < full; ++w) {
            unsigned x = wp[w];
            cA += cnt_eq(x, patA);
            cB += cnt_eq(x, patB);
        }
        if (lane & 1) { // 2 leftover bytes; upper -> 0xFF (never match b<=101)
            unsigned x = wp[full] | 0xFFFF0000u;
            cA += cnt_eq(x, patA);
            cB += cnt_eq(x, patB);
        }
        int pA = 0, pB = 0;
        for (int w = 0; w < wv; ++w) {
            pA += (b0 != 255) ? waveHist[w][b0] : 0;
            pB += (b1 != 255) ? waveHist[w][b1] : 0;
        }
        const int s0 = bid * SPB + 2 * tid;
        if (b0 != 255) {
            int pos = bstart[b0] + before[b0] + pA + cA;
            if (pos < N_IDS) order[pos] = s0;
        }
        if (b1 != 255) {
            int pos = bstart[b1] + before[b1] + pB + cB + ((b0 == b1) ? 1 : 0);
            if (pos < N_IDS) order[pos] = s0 + 1;
        }
    } else {
        // parallel chunk scans: chunk-local exclusive word prefixes
        __shared__ int lds8[8];
        const int j = bid - SB;
        const int w = j * NTHR + tid;
        int v = (w < NW) ? __popc(missBits[w]) : 0;
        int excl = block_exscan(v, tid, lds8);
        if (w < NW) wordPrefix[w] = excl;
        if (tid == NTHR - 1) blockSumMiss[j] = excl + v;
    }
}

// ---------------------------------------------------------------------------
// D4: translation + row gather; one wave per row. Cross-chunk miss prefix
// fixed up locally via a 62-lane shfl scan of blockSumMiss (validated R7).
// d_out[0:N) = (float)gpu_row_idxs ; d_out[N:] = gathered f32 rows
__global__ __launch_bounds__(NTHR) void final_k(
    const int* __restrict__ ids, const int* __restrict__ idx_map,
    const int* __restrict__ inv, const unsigned* __restrict__ missBits,
    const int* __restrict__ wordPrefix, const int* __restrict__ blockSumMiss,
    const int* __restrict__ order, const float* __restrict__ weight,
    const float* __restrict__ cuda_weight, float* __restrict__ out) {
    __shared__ int chunkPrefix[64];
    const int tid = threadIdx.x;
    if (tid < 64) { // first wave: exclusive scan of 62 chunk sums
        int v = (tid < MWB) ? blockSumMiss[tid] : 0;
        int incl = v;
#pragma unroll
        for (int o = 1; o < 64; o <<= 1) {
            int u = __shfl_up(incl, o, 64);
            if (tid >= o) incl += u;
        }
        chunkPrefix[tid] = incl - v;
    }
    __syncthreads();
    const int i = blockIdx.x * 8 + (tid >> 6); // wave index = row
    const int lane = tid & 63;
    int id = ids[i];
    int row = (id >= 0 && id < E_TOT) ? idx_map[id] : 0;
    row = row < 0 ? 0 : (row >= E_TOT ? E_TOT - 1 : row);
    int s0 = inv[row];
    int slot;
    const float* src;
    if (s0 >= 0) {
        slot = s0;
        src = cuda_weight + (size_t)slot * D_DIM;
    } else {
        int w = row >> 5;
        unsigned mask = (1u << (row & 31)) - 1u;
        int rank = chunkPrefix[w >> 9] + wordPrefix[w] +
                   __popc(missBits[w] & mask);
        rank = rank < 0 ? 0 : (rank >= N_IDS ? N_IDS - 1 : rank);
        slot = order[rank];
        src = weight + (size_t)row * D_DIM;
    }
    if (lane == 0) out[i] = (float)slot;
    const float2* s2 = (const float2*)src;
    float2* d2 = (float2*)(out + N_IDS + (size_t)i * D_DIM);
    d2[lane] = s2[lane]; // 64 lanes x float2 = 128 floats
}

// ---------------------------------------------------------------------------
extern "C" void kernel_launch(void* const* d_in, const int* in_sizes, int n_in,
                              void* d_out, int out_size, void* d_ws, size_t ws_size,
                              hipStream_t stream) {
    const int* ids     = (const int*)d_in[0];
    const int* idx_map = (const int*)d_in[1];
    const int* cidx    = (const int*)d_in[2]; // cached_idx_map
    const int* inv     = (const int*)d_in[3]; // inverted_cached_idx
    const int* freq    = (const int*)d_in[4]; // freq_cnter
    const float* weight      = (const float*)d_in[5];
    const float* cuda_weight = (const float*)d_in[6];
    float* out = (float*)d_out;

    unsigned char* ws = (unsigned char*)d_ws;
    size_t o = 0;
    auto take = [&](size_t bytes) {
        size_t r = o;
        o += (bytes + 255) & ~(size_t)255;
        return r;
    };
    // ---- zero region (single contiguous memset) ----
    unsigned* protBits = (unsigned*)(ws + take(C_CAP / 8));           // 32 KB
    unsigned* missBits = (unsigned*)(ws + take((size_t)NW * 4));      // 125 KB
    int* rawHist       = (int*)(ws + take((size_t)SB * NB * 4));      // 104 KB
    size_t zbytes = o;
    // ---- non-zeroed (plain stores every call; replay-safe) ----
    unsigned short* bucketArr2 = (unsigned short*)(ws + take(C_CAP)); // 256 KB
    int* wordPrefix   = (int*)(ws + take((size_t)NW * 4));            // 125 KB
    int* blockSumMiss = (int*)(ws + take(MWB * 4));
    int* order        = (int*)(ws + take((size_t)N_IDS * 4));         // 64 KB
    (void)ws_size; (void)in_sizes; (void)n_in; (void)out_size;

    // D1: zero masks + rawHist
    hipMemsetAsync(ws, 0, zbytes, stream);

    // D2: raw buckets + hist rows (0..255) || scatter + corrections (256..287)
    stage1_k<<<SB + N_IDS / NTHR, NTHR, 0, stream>>>(
        ids, idx_map, inv, cidx, freq, protBits, missBits, bucketArr2,
        rawHist);

    // D3: stable placement (0..255) || miss chunk scans (256..317)
    stage2_k<<<SB + MWB, NTHR, 0, stream>>>(bucketArr2, protBits, rawHist,
                                            missBits, wordPrefix,
                                            blockSumMiss, order);

    // D4: translation + gather (one wave per row; local chunk fixup)
    final_k<<<NGB, NTHR, 0, stream>>>(ids, idx_map, inv, missBits, wordPrefix,
                                      blockSumMiss, order, weight, cuda_weight,
                                      out);
}